// Round 12
// baseline (579.524 us; speedup 1.0000x reference)
//
#include <hip/hip_runtime.h>

// Pipeline: fused morph open+close (1 LDS kernel) -> conv1+bn1
//           -> conv2+pool+bn2 (tiled,chunked) -> conv3+bn3 -> conv4+globalmax
//           -> dense -> h_maxima (10x 5-step fused dilate+min)
// All fp32. Conv LDS sized for 8 blocks/CU (2048-thread cap): 2048-block grids
// run as ONE fully-resident round. All LDS float4 accesses 16B-aligned
// (pitches 48B/288B/320B; CHP=10 would be 8B-misaligned -> ds_*_b128 UB).

#define B_ 32
#define H_ 256
#define W_ 256

__device__ __forceinline__ float4 ld4(const float* p){ return *reinterpret_cast<const float4*>(p); }
__device__ __forceinline__ void st4(float* p, float4 v){ *reinterpret_cast<float4*>(p) = v; }
__device__ __forceinline__ void st4s(float* p, float4 v){ *reinterpret_cast<float4*>(p) = v; }

// ---------------- fused morphology: erode(ko)->dilate(ko)->dilate(kc)->erode(kc) ----------------
// 64x32 core, halo 4 -> 72x40 LDS tile, 2 buffers. Halo-shrink: after op k,
// tile-distance>=k positions valid; op k+1 at distance d reads d-1>=k. Core
// (distance>=4) exact after 4 ops. Out-of-image positions hold the NEXT op's
// identity, giving exact skip-OOB border semantics.
#define MF_W 72
#define MF_H 40
template<int IS_MAX>
__device__ __forceinline__ void morph_op(
    const float* __restrict__ cur, float* __restrict__ nxt,
    const float* __restrict__ k9, float ident_next,
    int gy0, int gx0, int tid)
{
    float kv[3][3];
    #pragma unroll
    for (int di = -1; di <= 1; ++di)
        #pragma unroll
        for (int dj = -1; dj <= 1; ++dj)
            kv[di + 1][dj + 1] = IS_MAX ? k9[(di + 1) * 3 + (dj + 1)]
                                        : k9[(1 - di) * 3 + (1 - dj)];
    const float INF = __builtin_inff();
    for (int i = tid; i < MF_H * (MF_W / 4); i += 256) {
        int r = i / (MF_W / 4), q = i - r * (MF_W / 4);
        int c = q * 4;
        float res[4];
        #pragma unroll
        for (int j = 0; j < 4; ++j) res[j] = IS_MAX ? -INF : INF;
        #pragma unroll
        for (int di = -1; di <= 1; ++di) {
            int rr = min(max(r + di, 0), MF_H - 1);       // clamp: garbage ring only
            const float* rw = cur + rr * MF_W;
            float w[6];
            w[0] = rw[(c > 0) ? c - 1 : 0];
            float4 a = *reinterpret_cast<const float4*>(rw + c);
            w[1] = a.x; w[2] = a.y; w[3] = a.z; w[4] = a.w;
            w[5] = rw[(c + 4 < MF_W) ? c + 4 : MF_W - 1];
            #pragma unroll
            for (int dj = -1; dj <= 1; ++dj) {
                float k = kv[di + 1][dj + 1];
                #pragma unroll
                for (int j = 0; j < 4; ++j) {
                    float v = IS_MAX ? (w[j + 1 + dj] + k) : (w[j + 1 + dj] - k);
                    res[j] = IS_MAX ? fmaxf(res[j], v) : fminf(res[j], v);
                }
            }
        }
        int gy = gy0 + r;
        #pragma unroll
        for (int j = 0; j < 4; ++j) {
            int gx = gx0 + c + j;
            bool in = (gy >= 0) && (gy < H_) && (gx >= 0) && (gx < W_);
            res[j] = in ? res[j] : ident_next;
        }
        *reinterpret_cast<float4*>(nxt + r * MF_W + c) =
            make_float4(res[0], res[1], res[2], res[3]);
    }
}

__global__ void __launch_bounds__(256) morphf_k(
    const float* __restrict__ x, float* __restrict__ xc,
    const float* __restrict__ ko, const float* __restrict__ kc)
{
    __shared__ float bufA[MF_H * MF_W];
    __shared__ float bufB[MF_H * MF_W];
    int blk = blockIdx.x;
    int img = blk >> 5; int tt = blk & 31; int ty = tt >> 2, tx = tt & 3;
    int gy0 = ty * 32 - 4, gx0 = tx * 64 - 4;
    int tid = threadIdx.x;
    const float* src = x + (size_t)img * (H_ * W_);
    const float INF = __builtin_inff();
    for (int i = tid; i < MF_H * MF_W; i += 256) {
        int r = i / MF_W, c = i - r * MF_W;
        int gy = gy0 + r, gx = gx0 + c;
        bool in = (gy >= 0) && (gy < H_) && (gx >= 0) && (gx < W_);
        bufA[i] = in ? src[gy * W_ + gx] : INF;            // erosion identity
    }
    __syncthreads();
    morph_op<0>(bufA, bufB, ko, -INF, gy0, gx0, tid);      // erode(ko);  next: dilate
    __syncthreads();
    morph_op<1>(bufB, bufA, ko, -INF, gy0, gx0, tid);      // dilate(ko); next: dilate
    __syncthreads();
    morph_op<1>(bufA, bufB, kc,  INF, gy0, gx0, tid);      // dilate(kc); next: erode
    __syncthreads();
    morph_op<0>(bufB, bufA, kc,  0.f, gy0, gx0, tid);      // erode(kc);  core all in-image
    __syncthreads();
    float* dst = xc + (size_t)img * (H_ * W_);
    for (int i = tid; i < 32 * 16; i += 256) {
        int r = i >> 4, q = i & 15;
        float4 v = *reinterpret_cast<const float4*>(bufA + (4 + r) * MF_W + 4 + q * 4);
        *reinterpret_cast<float4*>(dst + (ty * 32 + r) * W_ + tx * 64 + q * 4) = v;
    }
}

// ---------------- conv1 (3x3,1->8) + relu + bn1 ----------------
__global__ void conv1_k(const float* __restrict__ xc, float* __restrict__ y1,
                        const float* __restrict__ w, const float* __restrict__ bias,
                        const float* __restrict__ g, const float* __restrict__ bb,
                        const float* __restrict__ mn, const float* __restrict__ vr)
{
    const int S = 254;
    int t = blockIdx.x * blockDim.x + threadIdx.x;
    int total = B_ * S * S;
    if (t >= total) return;
    int x = t % S; int y = (t / S) % S; int b = t / (S * S);
    const float* img = xc + (size_t)b * H_ * W_;
    float acc[8];
    #pragma unroll
    for (int c = 0; c < 8; ++c) acc[c] = bias[c];
    #pragma unroll
    for (int ky = 0; ky < 3; ++ky) {
        #pragma unroll
        for (int kx = 0; kx < 3; ++kx) {
            float iv = img[(y + ky) * W_ + (x + kx)];
            const float* wp = w + (ky * 3 + kx) * 8;
            #pragma unroll
            for (int c = 0; c < 8; ++c) acc[c] = fmaf(iv, wp[c], acc[c]);
        }
    }
    float* op = y1 + (size_t)t * 8;
    #pragma unroll
    for (int c = 0; c < 8; ++c) {
        float z = fmaxf(acc[c], 0.f);
        float s = g[c] / sqrtf(vr[c] + 1.0e-3f);
        op[c] = fmaf(s, z, bb[c] - mn[c] * s);
    }
}

// ---------------- conv2 (3x3,8->16) + relu + maxpool2 + bn2, tiled+chunked ----------------
// Block: 16x16 pooled outputs (= 32x32 conv region), 34x34 tile, 2 chunks of 4 ch (SoA).
#define C2_PITCH (34 * 34 + 2)
__global__ void __launch_bounds__(256) conv2t_k(
    const float* __restrict__ y1, float* __restrict__ y2,
    const float* __restrict__ w, const float* __restrict__ bias,
    const float* __restrict__ g, const float* __restrict__ bb,
    const float* __restrict__ mn, const float* __restrict__ vr)
{
    const int SIN = 254, POUT = 126;
    __shared__ float lds[4 * C2_PITCH];    // 18.5 KB -> 8 blocks/CU
    int blk = blockIdx.x;
    int b = blk >> 6; int tt = blk & 63; int ty = tt >> 3, tx = tt & 7;
    int cy0 = ty * 32, cx0 = tx * 32;      // conv-output/tile-input origin
    int tid = threadIdx.x;
    int lty = tid >> 4, ltx = tid & 15;
    const float* in_b = y1 + (size_t)b * SIN * SIN * 8;

    float acc[4][16];
    #pragma unroll
    for (int pos = 0; pos < 4; ++pos)
        #pragma unroll
        for (int c = 0; c < 16; ++c) acc[pos][c] = bias[c];

    #pragma unroll 1
    for (int ch = 0; ch < 2; ++ch) {
        int ci0 = ch * 4;
        if (ch) __syncthreads();           // readers done before restage
        for (int i = tid; i < 34 * 34; i += 256) {
            int r = i / 34, c = i - r * 34;
            int gy = min(cy0 + r, SIN - 1), gx = min(cx0 + c, SIN - 1);  // clamp feeds masked lanes only
            float4 a = ld4(in_b + ((size_t)gy * SIN + gx) * 8 + ci0);
            lds[0 * C2_PITCH + i] = a.x; lds[1 * C2_PITCH + i] = a.y;
            lds[2 * C2_PITCH + i] = a.z; lds[3 * C2_PITCH + i] = a.w;
        }
        __syncthreads();
        #pragma unroll 1
        for (int tap = 0; tap < 9; ++tap) {
            int ky = tap / 3, kx = tap - ky * 3;
            const float* wp = w + (tap * 8 + ci0) * 16;
            #pragma unroll
            for (int pos = 0; pos < 4; ++pos) {
                int pix = (2 * lty + (pos >> 1) + ky) * 34 + (2 * ltx + (pos & 1) + kx);
                float in4[4];
                #pragma unroll
                for (int ci = 0; ci < 4; ++ci) in4[ci] = lds[ci * C2_PITCH + pix];
                #pragma unroll
                for (int ci = 0; ci < 4; ++ci)
                    #pragma unroll
                    for (int co = 0; co < 16; ++co)
                        acc[pos][co] = fmaf(in4[ci], wp[ci * 16 + co], acc[pos][co]);
            }
        }
    }

    int py = ty * 16 + lty, px = tx * 16 + ltx;
    if (py < POUT && px < POUT) {
        float* op = y2 + ((size_t)b * POUT * POUT + (size_t)py * POUT + px) * 16;
        #pragma unroll
        for (int co = 0; co < 16; ++co) {
            float bst = fmaxf(fmaxf(fmaxf(acc[0][co], 0.f), fmaxf(acc[1][co], 0.f)),
                              fmaxf(fmaxf(acc[2][co], 0.f), fmaxf(acc[3][co], 0.f)));
            float s = g[co] / sqrtf(vr[co] + 1.0e-3f);
            op[co] = fmaf(s, bst, bb[co] - mn[co] * s);
        }
    }
}

// ---------------- chunked tiled conv core: 16x16 outputs/block, 18x18x8 LDS chunks ----------------
// CHP=12 pitch: 48B (16B-aligned float4s; ~2-way banks = free); 15.55KB -> 8 blocks/CU.
template<int CIN, int NCH, int CHP, int SIN>
__device__ __forceinline__ void conv_tile_chunked(
    const float* __restrict__ in_b, const float* __restrict__ w,
    const float* __restrict__ bias, float* lds,
    int y0, int x0, int lty, int ltx, int tid, float acc[32])
{
    const int CHUNK = CIN / NCH, CHQ = CHUNK / 4;
    #pragma unroll
    for (int c = 0; c < 32; ++c) acc[c] = bias[c];
    #pragma unroll 1
    for (int ch = 0; ch < NCH; ++ch) {
        int ci0 = ch * CHUNK;
        if (ch) __syncthreads();           // all readers done before restage
        const int TOT = 18 * 18 * CHQ;
        for (int i = tid; i < TOT; i += 256) {
            int pix = i / CHQ, q = i - pix * CHQ;
            int r = pix / 18, c = pix - r * 18;
            int gy = min(y0 + r, SIN - 1), gx = min(x0 + c, SIN - 1);
            float4 v = ld4(in_b + ((size_t)gy * SIN + gx) * CIN + ci0 + q * 4);
            st4s(lds + (r * 18 + c) * CHP + q * 4, v);
        }
        __syncthreads();
        const float* wb = w + ci0 * 32;
        #pragma unroll 1
        for (int tap = 0; tap < 9; ++tap) {
            int ky = tap / 3, kx = tap - ky * 3;
            const float* lp = lds + ((lty + ky) * 18 + (ltx + kx)) * CHP;
            float v[CHUNK];
            #pragma unroll
            for (int q = 0; q < CHQ; ++q) {
                float4 t4 = *reinterpret_cast<const float4*>(lp + q * 4);
                v[q * 4 + 0] = t4.x; v[q * 4 + 1] = t4.y;
                v[q * 4 + 2] = t4.z; v[q * 4 + 3] = t4.w;
            }
            const float* wt = wb + tap * CIN * 32;
            #pragma unroll
            for (int ci = 0; ci < CHUNK; ++ci)
                #pragma unroll
                for (int co = 0; co < 32; ++co)
                    acc[co] = fmaf(v[ci], wt[ci * 32 + co], acc[co]);
        }
    }
}

// ---------------- conv3 (3x3,16->32) + relu + bn3, tiled+chunked ----------------
__global__ void __launch_bounds__(256) conv3t_k(
    const float* __restrict__ y2, float* __restrict__ y3,
    const float* __restrict__ w, const float* __restrict__ bias,
    const float* __restrict__ g, const float* __restrict__ bb,
    const float* __restrict__ mn, const float* __restrict__ vr)
{
    const int SIN = 126, SOUT = 124;      // 8x8 tiles
    __shared__ float lds[18 * 18 * 12];   // 15.55 KB -> 8 blocks/CU
    int blk = blockIdx.x;
    int b = blk >> 6; int tt = blk & 63; int ty = tt >> 3, tx = tt & 7;
    int tid = threadIdx.x, lty = tid >> 4, ltx = tid & 15;
    float acc[32];
    conv_tile_chunked<16, 2, 12, 126>(y2 + (size_t)b * SIN * SIN * 16, w, bias,
                                      lds, ty * 16, tx * 16, lty, ltx, tid, acc);
    int oy = ty * 16 + lty, ox = tx * 16 + ltx;
    if (oy < SOUT && ox < SOUT) {
        float* op = y3 + ((size_t)b * SOUT * SOUT + (size_t)oy * SOUT + ox) * 32;
        #pragma unroll
        for (int c = 0; c < 32; ++c) {
            float z = fmaxf(acc[c], 0.f);
            float s = g[c] / sqrtf(vr[c] + 1.0e-3f);
            op[c] = fmaf(s, z, bb[c] - mn[c] * s);
        }
    }
}

// ---------------- conv4 (3x3,32->32) + relu + global max per (b,c), tiled+chunked ----------------
__global__ void __launch_bounds__(256) conv4t_k(
    const float* __restrict__ y3, float* __restrict__ maxbuf,
    const float* __restrict__ w, const float* __restrict__ bias)
{
    const int SIN = 124, SOUT = 122;      // 8x8 tiles
    __shared__ float lds[18 * 18 * 12];   // 15.55 KB -> 8 blocks/CU
    __shared__ float red[4 * 32];
    int blk = blockIdx.x;
    int b = blk >> 6; int tt = blk & 63; int ty = tt >> 3, tx = tt & 7;
    int tid = threadIdx.x, lty = tid >> 4, ltx = tid & 15;
    float acc[32];
    conv_tile_chunked<32, 4, 12, 124>(y3 + (size_t)b * SIN * SIN * 32, w, bias,
                                      lds, ty * 16, tx * 16, lty, ltx, tid, acc);
    int oy = ty * 16 + lty, ox = tx * 16 + ltx;
    bool valid = (oy < SOUT) && (ox < SOUT);
    #pragma unroll
    for (int c = 0; c < 32; ++c)
        acc[c] = valid ? fmaxf(acc[c], 0.f) : 0.f;   // relu >= 0, masked lanes neutral
    int lane = tid & 63, wid = tid >> 6;
    #pragma unroll 1
    for (int c = 0; c < 32; ++c) {
        float v = acc[c];
        #pragma unroll
        for (int off = 32; off >= 1; off >>= 1)
            v = fmaxf(v, __shfl_xor(v, off, 64));
        if (lane == 0) red[wid * 32 + c] = v;
    }
    __syncthreads();
    if (tid < 32) {
        int c = tid;
        float mx = fmaxf(fmaxf(red[0 * 32 + c], red[1 * 32 + c]),
                         fmaxf(red[2 * 32 + c], red[3 * 32 + c]));
        atomicMax(reinterpret_cast<int*>(maxbuf) + b * 32 + c, __float_as_int(mx));
    }
}

// ---------------- dense: h[b] = dot(max[b,:], dense_w) + dense_b ----------------
__global__ void dense_k(const float* __restrict__ maxbuf, const float* __restrict__ dw,
                        const float* __restrict__ db, float* __restrict__ hbuf,
                        float* __restrict__ out_h)
{
    int t = threadIdx.x;
    if (t < B_) {
        float acc = db[0];
        #pragma unroll
        for (int c = 0; c < 32; ++c) acc = fmaf(maxbuf[t * 32 + c], dw[c], acc);
        hbuf[t] = acc;
        out_h[t] = acc;
    }
}

// ---------------- h_maxima marker init: m0 = xc - h[b] ----------------
__global__ void minit_k(const float* __restrict__ xc, const float* __restrict__ hbuf,
                        float* __restrict__ m0)
{
    int t = blockIdx.x * blockDim.x + threadIdx.x;
    int b = t >> 14;
    if (b >= B_) return;
    float hv = hbuf[b];
    float4 a = ld4(xc + (size_t)t * 4);
    st4(m0 + (size_t)t * 4, make_float4(a.x - hv, a.y - hv, a.z - hv, a.w - hv));
}

// ---------------- fused h_maxima: 5 steps of m = min(dilate3(m), mask) per launch ----------------
#define FS_R   5
#define FS_IW  80
#define FS_IH  42
__global__ void __launch_bounds__(256) fstep_k(
    const float* __restrict__ msrc, const float* __restrict__ mask,
    float* __restrict__ mdst)
{
    __shared__ float bufA[FS_IH * FS_IW];
    __shared__ float bufB[FS_IH * FS_IW];
    __shared__ float mk[FS_IH * FS_IW];
    const float NINF = -__builtin_inff();

    int blk = blockIdx.x;
    int img = blk >> 5; int tt = blk & 31; int ty = tt >> 2, tx = tt & 3;
    int gy0 = ty * 32 - FS_R;     // row halo = 5
    int gx0 = tx * 64 - 8;        // col halo = 8 (keeps 16B alignment of core)
    int tid = threadIdx.x;
    const float* src_b = msrc + (size_t)img * (H_ * W_);
    const float* msk_b = mask + (size_t)img * (H_ * W_);

    for (int i = tid; i < FS_IH * FS_IW; i += 256) {
        int r = i / FS_IW, c = i - r * FS_IW;
        int gy = gy0 + r, gx = gx0 + c;
        bool in = (gy >= 0) && (gy < H_) && (gx >= 0) && (gx < W_);
        int gidx = gy * W_ + gx;
        bufA[i] = in ? src_b[gidx] : NINF;
        mk[i]   = in ? msk_b[gidx] : NINF;
    }
    __syncthreads();

    float* cur = bufA;
    float* nxt = bufB;
    #pragma unroll 1
    for (int s = 0; s < FS_R; ++s) {
        for (int i = tid; i < FS_IH * (FS_IW / 4); i += 256) {
            int r = i / (FS_IW / 4), q = i - r * (FS_IW / 4);
            int c = q * 4;
            int rm = (r > 0) ? r - 1 : 0, rp = (r < FS_IH - 1) ? r + 1 : FS_IH - 1;
            float h0, h1, h2, h3;
            {
                const float* rw = cur + rm * FS_IW;
                float4 a = *reinterpret_cast<const float4*>(rw + c);
                float L = rw[(c > 0) ? c - 1 : 0];
                float R = rw[(c + 4 < FS_IW) ? c + 4 : FS_IW - 1];
                h0 = fmaxf(fmaxf(L, a.x), a.y);
                h1 = fmaxf(fmaxf(a.x, a.y), a.z);
                h2 = fmaxf(fmaxf(a.y, a.z), a.w);
                h3 = fmaxf(fmaxf(a.z, a.w), R);
            }
            {
                const float* rw = cur + r * FS_IW;
                float4 a = *reinterpret_cast<const float4*>(rw + c);
                float L = rw[(c > 0) ? c - 1 : 0];
                float R = rw[(c + 4 < FS_IW) ? c + 4 : FS_IW - 1];
                h0 = fmaxf(h0, fmaxf(fmaxf(L, a.x), a.y));
                h1 = fmaxf(h1, fmaxf(fmaxf(a.x, a.y), a.z));
                h2 = fmaxf(h2, fmaxf(fmaxf(a.y, a.z), a.w));
                h3 = fmaxf(h3, fmaxf(fmaxf(a.z, a.w), R));
            }
            {
                const float* rw = cur + rp * FS_IW;
                float4 a = *reinterpret_cast<const float4*>(rw + c);
                float L = rw[(c > 0) ? c - 1 : 0];
                float R = rw[(c + 4 < FS_IW) ? c + 4 : FS_IW - 1];
                h0 = fmaxf(h0, fmaxf(fmaxf(L, a.x), a.y));
                h1 = fmaxf(h1, fmaxf(fmaxf(a.x, a.y), a.z));
                h2 = fmaxf(h2, fmaxf(fmaxf(a.y, a.z), a.w));
                h3 = fmaxf(h3, fmaxf(fmaxf(a.z, a.w), R));
            }
            float4 m4 = *reinterpret_cast<const float4*>(mk + r * FS_IW + c);
            float4 o;
            o.x = fminf(h0, m4.x); o.y = fminf(h1, m4.y);
            o.z = fminf(h2, m4.z); o.w = fminf(h3, m4.w);
            *reinterpret_cast<float4*>(nxt + r * FS_IW + c) = o;
        }
        __syncthreads();
        float* tmp = cur; cur = nxt; nxt = tmp;
    }

    float* dst_b = mdst + (size_t)img * (H_ * W_);
    for (int i = tid; i < 32 * 16; i += 256) {
        int r = i >> 4, q = i & 15;
        float4 v = *reinterpret_cast<const float4*>(cur + (FS_R + r) * FS_IW + 8 + q * 4);
        *reinterpret_cast<float4*>(dst_b + (ty * 32 + r) * W_ + tx * 64 + q * 4) = v;
    }
}

extern "C" void kernel_launch(void* const* d_in, const int* in_sizes, int n_in,
                              void* d_out, int out_size, void* d_ws, size_t ws_size,
                              hipStream_t stream) {
    const float* x    = (const float*)d_in[0];
    const float* ko   = (const float*)d_in[1];
    const float* kc   = (const float*)d_in[2];
    const float* c1w  = (const float*)d_in[3];
    const float* c1b  = (const float*)d_in[4];
    const float* c2w  = (const float*)d_in[5];
    const float* c2b  = (const float*)d_in[6];
    const float* c3w  = (const float*)d_in[7];
    const float* c3b  = (const float*)d_in[8];
    const float* c4w  = (const float*)d_in[9];
    const float* c4b  = (const float*)d_in[10];
    const float* bn1g = (const float*)d_in[11];
    const float* bn1b = (const float*)d_in[12];
    const float* bn1m = (const float*)d_in[13];
    const float* bn1v = (const float*)d_in[14];
    const float* bn2g = (const float*)d_in[15];
    const float* bn2b = (const float*)d_in[16];
    const float* bn2m = (const float*)d_in[17];
    const float* bn2v = (const float*)d_in[18];
    const float* bn3g = (const float*)d_in[19];
    const float* bn3b = (const float*)d_in[20];
    const float* bn3m = (const float*)d_in[21];
    const float* bn3v = (const float*)d_in[22];
    const float* dw   = (const float*)d_in[23];
    const float* db   = (const float*)d_in[24];
    float* out = (float*)d_out;
    float* ws  = (float*)d_ws;

    // workspace layout (floats): xc [0,2M) | A [2M,18.6M) | Bbuf | maxbuf | hbuf
    float* xc     = ws;
    float* A      = ws + 2097152;
    float* Bbuf   = ws + 18613248;
    float* maxbuf = ws + 26741760;
    float* hbuf   = ws + 26742784;
    float* t0 = A;
    float* t1 = A + 2097152;

    const int NQ_BLOCKS = (B_ * H_ * W_ / 4) / 256;  // 2048

    // fused morphological open+close -> xc
    morphf_k<<<B_ * 32, 256, 0, stream>>>(x, xc, ko, kc);

    conv1_k<<<(B_ * 254 * 254 + 255) / 256, 256, 0, stream>>>(xc, A, c1w, c1b,
                                                              bn1g, bn1b, bn1m, bn1v);
    conv2t_k<<<B_ * 64, 256, 0, stream>>>(A, Bbuf, c2w, c2b, bn2g, bn2b, bn2m, bn2v);
    conv3t_k<<<B_ * 64, 256, 0, stream>>>(Bbuf, A, c3w, c3b, bn3g, bn3b, bn3m, bn3v);
    hipMemsetAsync(maxbuf, 0, 32 * 32 * sizeof(float), stream);
    conv4t_k<<<B_ * 64, 256, 0, stream>>>(A, maxbuf, c4w, c4b);
    dense_k<<<1, 64, 0, stream>>>(maxbuf, dw, db, hbuf, out + B_ * H_ * W_);

    // h-maxima: marker = xc - h; 10 launches x 5 fused steps; last writes d_out
    minit_k<<<NQ_BLOCKS, 256, 0, stream>>>(xc, hbuf, t0);
    for (int j = 0; j < 10; ++j) {
        const float* src = (j & 1) ? t1 : t0;
        float* dst = (j == 9) ? out : ((j & 1) ? t0 : t1);
        fstep_k<<<B_ * 32, 256, 0, stream>>>(src, xc, dst);
    }
}